// Round 5
// baseline (101.218 us; speedup 1.0000x reference)
//
#include <hip/hip_runtime.h>
#include <hip/hip_bf16.h>

// SpikingPolicyNet: B=8192, D_in=256, H=1024, D_out=64, T=15, TAU=20, V_TH=1
//
// Pipeline:
//  K0: W2 -> W2^T bf16 (2 MB, L2-resident gather target)
//  K1: bf16-MFMA x@W1.T; epilogue folds b1 and converts I1 to the closed-form
//      spike interval k = ceil(log2(1-1/I)/log2(0.95)) (1 byte/neuron, rows
//      packed 4-per-u32). Spikes occur at t = k,2k,... (I1 time-invariant).
//  K2: per row: bucket spiking neurons by k; single gather pass accumulates
//      per-bucket column sums G_k and the spike-free bound
//      U = b2 + sum_k max(G_k,0) >= max_t I2_t. Induction: v2_t <= U(1-.95^t),
//      so U <= 0.999 (margin >> fp32 drift) proves zero s2 spikes -> skip the
//      entire time loop (~97% of waves). Rare non-skip waves run an exact
//      per-step re-gather simulation. Readout fast path (out = bout,
//      bit-exact) when the row has no s2 spikes.

#define B_SZ   8192
#define D_IN   256
#define H_SZ   1024
#define D_OUT  64
#define T_STEPS 15
#define SKIP_THR 0.999f

typedef __attribute__((ext_vector_type(8))) short short8;
typedef __attribute__((ext_vector_type(4))) float f32x4;

static __device__ __forceinline__ unsigned int pk_bf16(float lo, float hi) {
    return (__builtin_bit_cast(unsigned int, hi) & 0xffff0000u) |
           (__builtin_bit_cast(unsigned int, lo) >> 16);
}

static __device__ __forceinline__ f32x4 unpack4(uint2 w) {
    f32x4 r;
    r.x = __builtin_bit_cast(float, w.x << 16);
    r.y = __builtin_bit_cast(float, w.x & 0xffff0000u);
    r.z = __builtin_bit_cast(float, w.y << 16);
    r.w = __builtin_bit_cast(float, w.y & 0xffff0000u);
    return r;
}

// ---------------------------------------------------------------- K0: W2 -> W2cb (transpose + bf16)
__global__ __launch_bounds__(256) void k0_transpose(const float* __restrict__ W2,
                                                    unsigned short* __restrict__ W2cb) {
    __shared__ float tile[32][33];
    const int bx = blockIdx.x * 32;
    const int by = blockIdx.y * 32;
    const int tx = threadIdx.x;
    const int ty = threadIdx.y;
    #pragma unroll
    for (int i = ty; i < 32; i += 8)
        tile[i][tx] = W2[(by + i) * H_SZ + bx + tx];
    __syncthreads();
    #pragma unroll
    for (int i = ty; i < 32; i += 8)
        W2cb[(bx + i) * H_SZ + by + tx] =
            (unsigned short)(__builtin_bit_cast(unsigned int, tile[tx][i]) >> 16);
}

// ---------------------------------------------------------------- K1: interval bytes from x@W1.T+b1
// kmat layout: u32 at [rowgroup][col] holds bytes for rows 4*rg..4*rg+3.
__global__ __launch_bounds__(256) void k1_mfma(const float* __restrict__ A,
                                               const float* __restrict__ Bw,
                                               const float* __restrict__ b1,
                                               unsigned int* __restrict__ kmat) {
    __shared__ unsigned int As4[2048];   // 128 rows x 32 bf16, 16B-chunk XOR swizzle
    __shared__ unsigned int Bs4[2048];
    const int tid  = threadIdx.x;
    const int m0   = blockIdx.x * 128;
    const int n0   = blockIdx.y * 128;
    const int lane = tid & 63;
    const int wid  = tid >> 6;
    const int wr   = wid >> 1, wc = wid & 1;

    const int row0 = tid >> 2;
    const int row1 = row0 + 64;
    const int q0   = tid & 3;

    f32x4 acc[4][4] = {};
    float4 s0[8], s1[8];

    auto LOAD = [&](float4* s, int kb) {
        const float* pa0 = A  + (m0 + row0) * D_IN + kb + q0 * 8;
        const float* pa1 = A  + (m0 + row1) * D_IN + kb + q0 * 8;
        const float* pb0 = Bw + (n0 + row0) * D_IN + kb + q0 * 8;
        const float* pb1 = Bw + (n0 + row1) * D_IN + kb + q0 * 8;
        s[0] = *(const float4*)pa0; s[1] = *(const float4*)(pa0 + 4);
        s[2] = *(const float4*)pa1; s[3] = *(const float4*)(pa1 + 4);
        s[4] = *(const float4*)pb0; s[5] = *(const float4*)(pb0 + 4);
        s[6] = *(const float4*)pb1; s[7] = *(const float4*)(pb1 + 4);
    };
    auto WRITE = [&](const float4* s) {
        const int i0 = row0 * 16 + (q0 ^ ((row0 >> 1) & 3)) * 4;
        const int i1 = row1 * 16 + (q0 ^ ((row1 >> 1) & 3)) * 4;
        *(uint4*)&As4[i0] = make_uint4(pk_bf16(s[0].x, s[0].y), pk_bf16(s[0].z, s[0].w),
                                       pk_bf16(s[1].x, s[1].y), pk_bf16(s[1].z, s[1].w));
        *(uint4*)&As4[i1] = make_uint4(pk_bf16(s[2].x, s[2].y), pk_bf16(s[2].z, s[2].w),
                                       pk_bf16(s[3].x, s[3].y), pk_bf16(s[3].z, s[3].w));
        *(uint4*)&Bs4[i0] = make_uint4(pk_bf16(s[4].x, s[4].y), pk_bf16(s[4].z, s[4].w),
                                       pk_bf16(s[5].x, s[5].y), pk_bf16(s[5].z, s[5].w));
        *(uint4*)&Bs4[i1] = make_uint4(pk_bf16(s[6].x, s[6].y), pk_bf16(s[6].z, s[6].w),
                                       pk_bf16(s[7].x, s[7].y), pk_bf16(s[7].z, s[7].w));
    };
    auto COMPUTE = [&]() {
        short8 afr[4], bfr[4];
        const int q  = lane >> 4;
        const int lr = lane & 15;
        #pragma unroll
        for (int mf = 0; mf < 4; ++mf) {
            const int ra = wr * 64 + mf * 16 + lr;
            afr[mf] = *(const short8*)&As4[ra * 16 + (q ^ ((ra >> 1) & 3)) * 4];
            const int rb = wc * 64 + mf * 16 + lr;
            bfr[mf] = *(const short8*)&Bs4[rb * 16 + (q ^ ((rb >> 1) & 3)) * 4];
        }
        #pragma unroll
        for (int mf = 0; mf < 4; ++mf)
            #pragma unroll
            for (int nf = 0; nf < 4; ++nf)
                acc[mf][nf] = __builtin_amdgcn_mfma_f32_16x16x32_bf16(
                    afr[mf], bfr[nf], acc[mf][nf], 0, 0, 0);
    };

    LOAD(s0, 0);
    for (int kb = 0; kb < D_IN; kb += 64) {
        if (kb + 32 < D_IN) LOAD(s1, kb + 32);
        __syncthreads();
        WRITE(s0);
        __syncthreads();
        COMPUTE();
        if (kb + 64 < D_IN) LOAD(s0, kb + 64);
        __syncthreads();
        WRITE(s1);
        __syncthreads();
        COMPUTE();
    }

    // Epilogue: I = acc + b1[col]; k = ceil(log2(1-1/I) * -13.5134035), 0 = no spike.
    // C/D layout (m89): col = lane&15, row = (lane>>4)*4 + r  -> 4 packed rows/u32.
    const int lr = lane & 15;
    const int qq = lane >> 4;
    float b1v[4];
    #pragma unroll
    for (int nf = 0; nf < 4; ++nf) b1v[nf] = b1[n0 + wc * 64 + nf * 16 + lr];

    #pragma unroll
    for (int mf = 0; mf < 4; ++mf) {
        const int rg = ((m0 + wr * 64 + mf * 16) >> 2) + qq;   // row-group
        #pragma unroll
        for (int nf = 0; nf < 4; ++nf) {
            const int c = n0 + wc * 64 + nf * 16 + lr;
            unsigned int pk = 0;
            #pragma unroll
            for (int r = 0; r < 4; ++r) {
                const float I = acc[mf][nf][r] + b1v[nf];
                int k = 0;
                if (I > 1.8632055f) {                      // t=15 threshold guard
                    const float l2 = __builtin_amdgcn_logf(1.0f - __builtin_amdgcn_rcpf(I));
                    int kc = (int)__builtin_ceilf(l2 * -13.5134035f);
                    k = kc < 1 ? 1 : (kc > 15 ? 15 : kc);
                }
                pk |= (unsigned int)k << (r * 8);
            }
            kmat[(size_t)rg * H_SZ + c] = pk;
        }
    }
}

// ---------------------------------------------------------------- K2: bucketed SNN + skip bound + readout
__global__ __launch_bounds__(256) void k2_snn(const unsigned int* __restrict__ kmat,
                                              const unsigned short* __restrict__ W2cb,
                                              const float* __restrict__ b2,
                                              const float* __restrict__ Wout,
                                              const float* __restrict__ bout,
                                              float* __restrict__ out) {
    const int b   = blockIdx.x;
    const int tid = threadIdx.x;
    const int j0  = tid * 4;

    __shared__ unsigned short list_s[H_SZ];
    __shared__ int cnt_s[16];
    __shared__ int curs_s[16];
    __shared__ int start_s[16];
    __shared__ int tot_s;
    __shared__ float rrow[H_SZ];

    // interval bytes for this row's 4 neurons (one uint4, byte (b&3) of each u32)
    const uint4 kv = *(const uint4*)&kmat[(size_t)(b >> 2) * H_SZ + j0];
    const int sh = (b & 3) * 8;
    const int ku0 = (int)((kv.x >> sh) & 0xffu);
    const int ku1 = (int)((kv.y >> sh) & 0xffu);
    const int ku2 = (int)((kv.z >> sh) & 0xffu);
    const int ku3 = (int)((kv.w >> sh) & 0xffu);

    const float4 b2v = *(const float4*)&b2[j0];

    if (tid < 16) { cnt_s[tid] = 0; if (tid == 0) tot_s = 0; }
    __syncthreads();
    if (ku0) atomicAdd(&cnt_s[ku0], 1);
    if (ku1) atomicAdd(&cnt_s[ku1], 1);
    if (ku2) atomicAdd(&cnt_s[ku2], 1);
    if (ku3) atomicAdd(&cnt_s[ku3], 1);
    __syncthreads();
    if (tid < 16) {
        int s = 0;
        for (int i = 1; i < tid; ++i) s += cnt_s[i];
        start_s[tid] = s;
        curs_s[tid]  = s;
    }
    __syncthreads();
    if (ku0) { int x = atomicAdd(&curs_s[ku0], 1); list_s[x] = (unsigned short)(j0 + 0); }
    if (ku1) { int x = atomicAdd(&curs_s[ku1], 1); list_s[x] = (unsigned short)(j0 + 1); }
    if (ku2) { int x = atomicAdd(&curs_s[ku2], 1); list_s[x] = (unsigned short)(j0 + 2); }
    if (ku3) { int x = atomicAdd(&curs_s[ku3], 1); list_s[x] = (unsigned short)(j0 + 3); }
    __syncthreads();

    // ---- Pass 1: gather once per spiking neuron; accumulate the spike-free
    //      bound U = b2 + sum_k max(G_k, 0)  (>= I2_t for every t).
    f32x4 U4;
    U4.x = b2v.x; U4.y = b2v.y; U4.z = b2v.z; U4.w = b2v.w;

    #pragma unroll
    for (int k = 1; k <= 15; ++k) {
        const int e0 = __builtin_amdgcn_readfirstlane(start_s[k]);
        const int n  = __builtin_amdgcn_readfirstlane(cnt_s[k]);
        f32x4 g; g.x = 0.f; g.y = 0.f; g.z = 0.f; g.w = 0.f;
        int i = 0;
        for (; i + 3 < n; i += 4) {   // 4 loads in flight
            const int ja = __builtin_amdgcn_readfirstlane((int)list_s[e0 + i]);
            const int jb = __builtin_amdgcn_readfirstlane((int)list_s[e0 + i + 1]);
            const int jc = __builtin_amdgcn_readfirstlane((int)list_s[e0 + i + 2]);
            const int jd = __builtin_amdgcn_readfirstlane((int)list_s[e0 + i + 3]);
            const uint2 wa = *(const uint2*)(W2cb + ((size_t)ja << 10) + j0);
            const uint2 wb = *(const uint2*)(W2cb + ((size_t)jb << 10) + j0);
            const uint2 wc_ = *(const uint2*)(W2cb + ((size_t)jc << 10) + j0);
            const uint2 wd = *(const uint2*)(W2cb + ((size_t)jd << 10) + j0);
            g += unpack4(wa); g += unpack4(wb); g += unpack4(wc_); g += unpack4(wd);
        }
        for (; i < n; ++i) {
            const int ja = __builtin_amdgcn_readfirstlane((int)list_s[e0 + i]);
            const uint2 wa = *(const uint2*)(W2cb + ((size_t)ja << 10) + j0);
            g += unpack4(wa);
        }
        U4.x += fmaxf(g.x, 0.f);
        U4.y += fmaxf(g.y, 0.f);
        U4.z += fmaxf(g.z, 0.f);
        U4.w += fmaxf(g.w, 0.f);
    }

    // ---- Pass 2 (rare, ~3% of waves): exact per-step simulation with
    //      per-step re-gather (keeps G[15] out of the static VGPR budget).
    const bool need = (U4.x > SKIP_THR) || (U4.y > SKIP_THR) ||
                      (U4.z > SKIP_THR) || (U4.w > SKIP_THR);
    int c0 = 0, c1 = 0, c2 = 0, c3 = 0;
    if (__ballot(need)) {
        f32x4 v2; v2.x = 0.f; v2.y = 0.f; v2.z = 0.f; v2.w = 0.f;
        #pragma unroll
        for (int t = 1; t <= T_STEPS; ++t) {
            f32x4 i2; i2.x = b2v.x; i2.y = b2v.y; i2.z = b2v.z; i2.w = b2v.w;
            #pragma unroll
            for (int k = 1; k <= 15; ++k) {
                if (t % k == 0) {                       // compile-time folded
                    const int e0 = __builtin_amdgcn_readfirstlane(start_s[k]);
                    const int n  = __builtin_amdgcn_readfirstlane(cnt_s[k]);
                    for (int i = 0; i < n; ++i) {
                        const int j = __builtin_amdgcn_readfirstlane((int)list_s[e0 + i]);
                        const uint2 w = *(const uint2*)(W2cb + ((size_t)j << 10) + j0);
                        i2 += unpack4(w);
                    }
                }
            }
            v2 = v2 * 0.95f + i2 * 0.05f;
            if (v2.x > 1.0f) { v2.x = 0.f; ++c0; }
            if (v2.y > 1.0f) { v2.y = 0.f; ++c1; }
            if (v2.z > 1.0f) { v2.z = 0.f; ++c2; }
            if (v2.w > 1.0f) { v2.w = 0.f; ++c3; }
        }
    }

    // ---- readout
    const int my = c0 + c1 + c2 + c3;
    if (my) atomicAdd(&tot_s, my);
    __syncthreads();

    if (tot_s == 0) {                    // fast path: out = bout (bit-exact)
        if (tid < D_OUT) out[b * D_OUT + tid] = bout[tid];
        return;
    }

    rrow[j0 + 0] = (float)c0 / 15.0f;
    rrow[j0 + 1] = (float)c1 / 15.0f;
    rrow[j0 + 2] = (float)c2 / 15.0f;
    rrow[j0 + 3] = (float)c3 / 15.0f;
    __syncthreads();
    if (tid < D_OUT) {
        float acc = bout[tid];
        const float* wr = Wout + tid * H_SZ;
        for (int j = 0; j < H_SZ; ++j) acc = fmaf(rrow[j], wr[j], acc);
        out[b * D_OUT + tid] = acc;
    }
}

// ---------------------------------------------------------------- launch
extern "C" void kernel_launch(void* const* d_in, const int* in_sizes, int n_in,
                              void* d_out, int out_size, void* d_ws, size_t ws_size,
                              hipStream_t stream) {
    const float* x    = (const float*)d_in[0];
    const float* W1   = (const float*)d_in[1];
    const float* b1   = (const float*)d_in[2];
    const float* W2   = (const float*)d_in[3];
    const float* b2   = (const float*)d_in[4];
    const float* Wout = (const float*)d_in[5];
    const float* bout = (const float*)d_in[6];
    float* out = (float*)d_out;

    unsigned short* W2cb = (unsigned short*)d_ws;              // 2 MB bf16 W2^T
    unsigned int*   kmat = (unsigned int*)((char*)d_ws + (4 << 20)); // 8 MB intervals

    k0_transpose<<<dim3(H_SZ / 32, H_SZ / 32), dim3(32, 8), 0, stream>>>(W2, W2cb);
    k1_mfma<<<dim3(B_SZ / 128, H_SZ / 128), 256, 0, stream>>>(x, W1, b1, kmat);
    k2_snn<<<B_SZ, 256, 0, stream>>>(kmat, W2cb, b2, Wout, bout, out);
}